// Round 1
// baseline (74147.546 us; speedup 1.0000x reference)
//
#include <hip/hip_runtime.h>
#include <hip/hip_cooperative_groups.h>

namespace cg = cooperative_groups;

constexpr int BB    = 64;    // batch
constexpr int TT    = 1024;  // timesteps
constexpr int DIN_  = 256;
constexpr int H0    = 512;   // layer0 hidden
constexpr int H1    = 256;   // layer1 hidden (DOUT)
constexpr int KTOT  = 768;   // fused K for both layers (DIN+H0 and H0+H1)
constexpr int TILE  = 128;
constexpr int NTILES = 6;
constexpr int NWG0  = 128;   // layer0 WGs, 4 cols each
constexpr int NWG   = 256;
constexpr int NTHR  = 256;
constexpr int ILD   = TILE + 1;  // LDS row stride (129: conflict-free b32 reads)

__device__ __forceinline__ float sig_(float x) { return 1.0f / (1.0f + __expf(-x)); }
__device__ __forceinline__ float tanh_(float x) {
    float e = __expf(2.0f * x);
    return 1.0f - 2.0f / (e + 1.0f);   // inf-safe: x>>0 -> 1, x<<0 -> -1
}

template<int JW>
__device__ __forceinline__ void dot_tile(float acc[4], const float* __restrict__ inrow,
                                         const float* __restrict__ wt) {
    #pragma unroll 2
    for (int k = 0; k < TILE; k += 4) {
        const float a0 = inrow[k + 0];
        const float a1 = inrow[k + 1];
        const float a2 = inrow[k + 2];
        const float a3 = inrow[k + 3];
        #pragma unroll
        for (int jj = 0; jj < JW; jj++) {
            const float4 w4 = *(const float4*)(wt + jj * KTOT + k);
            acc[jj] = fmaf(a0, w4.x, acc[jj]);
            acc[jj] = fmaf(a1, w4.y, acc[jj]);
            acc[jj] = fmaf(a2, w4.z, acc[jj]);
            acc[jj] = fmaf(a3, w4.w, acc[jj]);
        }
    }
}

__global__ void __launch_bounds__(NTHR)
lstm_persist(const float* __restrict__ x,
             const float* __restrict__ Wih0, const float* __restrict__ bih0,
             const float* __restrict__ Whh0, const float* __restrict__ bhh0,
             const float* __restrict__ Wih1, const float* __restrict__ bih1,
             const float* __restrict__ Whh1, const float* __restrict__ bhh1,
             float* h1buf, float* h2buf, float* out)
{
    __shared__ float w_lds[16 * KTOT];      // 48 KB: this WG's weight cols
    __shared__ float in_lds[BB * ILD];      // 33 KB: staged input K-tile
    __shared__ float gates_lds[16 * BB];    // 4 KB

    const int tid  = threadIdx.x;
    const int wg   = blockIdx.x;
    const bool isL0 = (wg < NWG0);
    const int lw   = isL0 ? wg : wg - NWG0;
    const int jw   = isL0 ? 4 : 2;
    const int Hl   = isL0 ? H0 : H1;
    const int jbase = lw * jw;
    const int b = tid & 63;
    const int g = tid >> 6;                 // gate index 0..3 (wave id)

    // ---- prologue: cache this WG's weight columns in LDS (strided, once) ----
    {
        const float* Wi = isL0 ? Wih0 : Wih1;
        const float* Wh = isL0 ? Whh0 : Whh1;
        const int Ki  = isL0 ? DIN_ : H0;   // rows from W_ih: 256 / 512
        const int ldw = 4 * Hl;             // 2048 / 1024
        const int lg2 = isL0 ? 2 : 1;
        const int ncol = 4 * jw;
        for (int i = tid; i < ncol * KTOT; i += NTHR) {
            const int cc = i / KTOT;
            const int k  = i - cc * KTOT;
            const int gg = cc >> lg2;
            const int jj = cc & (jw - 1);
            const int c  = gg * Hl + jbase + jj;
            const float v = (k < Ki) ? Wi[(size_t)k * ldw + c]
                                     : Wh[(size_t)(k - Ki) * ldw + c];
            w_lds[cc * KTOT + k] = v;
        }
    }
    float bsum[4] = {0.f, 0.f, 0.f, 0.f};
    {
        const float* bi = isL0 ? bih0 : bih1;
        const float* bh = isL0 ? bhh0 : bhh1;
        for (int jj = 0; jj < jw; jj++) {
            const int c = g * Hl + jbase + jj;
            bsum[jj] = bi[c] + bh[c];
        }
    }
    float creg = 0.0f;                      // cell state: thread (b, jj=tid>>6)
    __syncthreads();

    cg::grid_group grid = cg::this_grid();

    const int r = tid >> 2;                 // staging row (batch)
    const int q = tid & 3;                  // quarter of the 128-col tile

    for (int it = 0; it <= TT; ++it) {
        // pipeline: layer0 computes step it, layer1 computes step it-1
        const bool active = isL0 ? (it < TT) : (it >= 1);
        if (active) {
            const int s = isL0 ? it : it - 1;
            float acc[4] = {bsum[0], bsum[1], bsum[2], bsum[3]};
            for (int tt = 0; tt < NTILES; ++tt) {
                const int kt = tt * TILE;
                const float* src;
                if (isL0) {
                    if (tt < 2) src = x + ((size_t)r * TT + s) * DIN_ + kt;
                    else        src = h1buf + ((s + 1) & 1) * (BB * H0) + r * H0 + (kt - DIN_);
                } else {
                    if (tt < 4) src = h1buf + (s & 1) * (BB * H0) + r * H0 + kt;
                    else        src = h2buf + ((s + 1) & 1) * (BB * H1) + r * H1 + (kt - H0);
                }
                __syncthreads();            // previous tile's readers done
                float* dst = &in_lds[r * ILD];
                #pragma unroll
                for (int ii = 0; ii < 8; ++ii) {
                    const int col = q * 32 + ii * 4;
                    const float4 v = *(const float4*)(src + col);
                    dst[col + 0] = v.x;
                    dst[col + 1] = v.y;
                    dst[col + 2] = v.z;
                    dst[col + 3] = v.w;
                }
                __syncthreads();
                const float* inrow = &in_lds[b * ILD];
                const float* wt    = &w_lds[(g * jw) * KTOT + kt];
                if (isL0) dot_tile<4>(acc, inrow, wt);
                else      dot_tile<2>(acc, inrow, wt);
            }
            __syncthreads();
            for (int jj = 0; jj < jw; jj++)
                gates_lds[(jj * 4 + g) * BB + b] = acc[jj];
            __syncthreads();
            if (tid < BB * jw) {
                const int jj = tid >> 6;
                const int bb = tid & 63;
                const float gi = gates_lds[(jj * 4 + 0) * BB + bb];
                const float gf = gates_lds[(jj * 4 + 1) * BB + bb];
                const float gG = gates_lds[(jj * 4 + 2) * BB + bb];
                const float go = gates_lds[(jj * 4 + 3) * BB + bb];
                const float cn = sig_(gf) * creg + sig_(gi) * tanh_(gG);
                const float hn = sig_(go) * tanh_(cn);
                creg = cn;
                const int j = jbase + jj;
                if (isL0) {
                    __hip_atomic_store(&h1buf[(s & 1) * (BB * H0) + bb * H0 + j], hn,
                                       __ATOMIC_RELAXED, __HIP_MEMORY_SCOPE_AGENT);
                } else {
                    __hip_atomic_store(&h2buf[(s & 1) * (BB * H1) + bb * H1 + j], hn,
                                       __ATOMIC_RELAXED, __HIP_MEMORY_SCOPE_AGENT);
                    out[((size_t)bb * TT + s) * H1 + j] = hn;
                }
            }
        }
        __threadfence();
        grid.sync();
    }
}

__global__ void zero_ws(float* p, int n) {
    const int i = blockIdx.x * blockDim.x + threadIdx.x;
    if (i < n) p[i] = 0.0f;
}

extern "C" void kernel_launch(void* const* d_in, const int* in_sizes, int n_in,
                              void* d_out, int out_size, void* d_ws, size_t ws_size,
                              hipStream_t stream) {
    const float* x    = (const float*)d_in[0];
    const float* Wih0 = (const float*)d_in[1];
    const float* bih0 = (const float*)d_in[2];
    const float* Whh0 = (const float*)d_in[3];
    const float* bhh0 = (const float*)d_in[4];
    const float* Wih1 = (const float*)d_in[5];
    const float* bih1 = (const float*)d_in[6];
    const float* Whh1 = (const float*)d_in[7];
    const float* bhh1 = (const float*)d_in[8];

    float* h1buf = (float*)d_ws;                 // 2 x 64 x 512
    float* h2buf = h1buf + 2 * BB * H0;          // 2 x 64 x 256
    float* out   = (float*)d_out;

    const int nz = 2 * BB * H0 + 2 * BB * H1;    // 98304 floats
    hipLaunchKernelGGL(zero_ws, dim3((nz + NTHR - 1) / NTHR), dim3(NTHR), 0, stream,
                       h1buf, nz);

    void* args[] = { (void*)&x,
                     (void*)&Wih0, (void*)&bih0, (void*)&Whh0, (void*)&bhh0,
                     (void*)&Wih1, (void*)&bih1, (void*)&Whh1, (void*)&bhh1,
                     (void*)&h1buf, (void*)&h2buf, (void*)&out };
    hipLaunchCooperativeKernel((void*)lstm_persist, dim3(NWG), dim3(NTHR),
                               args, 0, stream);
}

// Round 4
// 18439.162 us; speedup vs baseline: 4.0212x; 4.0212x over previous
//
#include <hip/hip_runtime.h>

// ---------------------------------------------------------------------------
// V2.2: persistent MFMA LSTM.
//  - f16 two-plane split (hi/lo), 3 x mfma_f32_16x16x32_f16 per k-tile
//  - hi-plane weights in VGPRs, lo-plane weights in LDS (one shared copy)
//  - PLAIN launch (no cooperative API): sync via agent-scope counters,
//    relaxed spin + one acquire; co-residency by construction (192 WG,
//    24KB LDS, ~200 VGPR -> >=1 WG/CU guaranteed)
//  - L0: WGs 0..127 (16 gate-cols each), L1: WGs 128..191, pipelined 1 step
// ---------------------------------------------------------------------------

constexpr int BB   = 64;
constexpr int TT   = 1024;
constexpr int DIN  = 256;
constexpr int H0   = 512;
constexpr int H1   = 256;
constexpr int NWG0 = 128;
constexpr int NWG1 = 64;
constexpr int NWG  = NWG0 + NWG1;
constexpr int NTHR = 256;
constexpr int NKT  = 24;       // K = 768 = 24 tiles of 32

typedef _Float16 v8h __attribute__((ext_vector_type(8)));
typedef __fp16   v2p __attribute__((ext_vector_type(2)));   // cvt_pkrtz result type
typedef float    v4f __attribute__((ext_vector_type(4)));
typedef unsigned int v4u __attribute__((ext_vector_type(4)));

union U1 { unsigned u; v2p h; };
union U4 { v4u u; v8h h; };

__device__ __forceinline__ unsigned pk2(float a, float b){
  U1 c; c.h = __builtin_amdgcn_cvt_pkrtz(a, b); return c.u;
}
__device__ __forceinline__ float lo16(unsigned u){ U1 c; c.u = u; return (float)c.h[0]; }
__device__ __forceinline__ float hi16(unsigned u){ U1 c; c.u = u; return (float)c.h[1]; }
__device__ __forceinline__ v8h as_h8(v4u u){ U4 c; c.u = u; return c.h; }

__device__ __forceinline__ v4f mfma16(v8h a, v8h b, v4f c){
  return __builtin_amdgcn_mfma_f32_16x16x32_f16(a, b, c, 0, 0, 0);
}

__device__ __forceinline__ float sigf(float v){ return 1.0f / (1.0f + __expf(-v)); }
__device__ __forceinline__ float tanhf_(float v){
  float e = __expf(2.0f * v);
  return 1.0f - 2.0f / (e + 1.0f);     // inf-safe
}

// relaxed poll (no per-iteration cache invalidate), one acquire at the end
__device__ __forceinline__ void spinw(const unsigned* p, unsigned tgt){
  while (__hip_atomic_load(p, __ATOMIC_RELAXED, __HIP_MEMORY_SCOPE_AGENT) < tgt)
    __builtin_amdgcn_s_sleep(2);
  (void)__hip_atomic_load(p, __ATOMIC_ACQUIRE, __HIP_MEMORY_SCOPE_AGENT);
}

// pack two pair-dword quads into hi-plane / lo-plane A fragments
__device__ __forceinline__ void frag_from_pairs(v4u p0, v4u p1, v8h& A, v8h& B){
  v4u ua, ub;
  ua[0] = __builtin_amdgcn_perm(p0[1], p0[0], 0x05040100u);
  ua[1] = __builtin_amdgcn_perm(p0[3], p0[2], 0x05040100u);
  ua[2] = __builtin_amdgcn_perm(p1[1], p1[0], 0x05040100u);
  ua[3] = __builtin_amdgcn_perm(p1[3], p1[2], 0x05040100u);
  ub[0] = __builtin_amdgcn_perm(p0[1], p0[0], 0x07060302u);
  ub[1] = __builtin_amdgcn_perm(p0[3], p0[2], 0x07060302u);
  ub[2] = __builtin_amdgcn_perm(p1[1], p1[0], 0x07060302u);
  ub[3] = __builtin_amdgcn_perm(p1[3], p1[2], 0x07060302u);
  A = as_h8(ua); B = as_h8(ub);
}

__device__ __forceinline__ void frag_from_floats(v4f f0, v4f f1, v8h& A, v8h& B){
  float v[8] = { f0[0], f0[1], f0[2], f0[3], f1[0], f1[1], f1[2], f1[3] };
  v4u ua, ub;
  #pragma unroll
  for (int d = 0; d < 4; ++d){
    unsigned p = pk2(v[2*d], v[2*d+1]);
    ua[d] = p;
    ub[d] = pk2(v[2*d] - lo16(p), v[2*d+1] - hi16(p));
  }
  A = as_h8(ua); B = as_h8(ub);
}

__global__ void __launch_bounds__(NTHR, 1)
lstm_mfma(const float* __restrict__ x, const unsigned* __restrict__ xp, int use_xp,
          const float* __restrict__ Wih0, const float* __restrict__ bih0,
          const float* __restrict__ Whh0, const float* __restrict__ bhh0,
          const float* __restrict__ Wih1, const float* __restrict__ bih1,
          const float* __restrict__ Whh1, const float* __restrict__ bhh1,
          unsigned* h1p, unsigned* h2p,
          unsigned* cnt0, unsigned* cnt1,
          float* out)
{
  __shared__ v4u wfbs[NKT * 64];       // 24 KB: lo-plane weight B-fragments

  const int tid   = threadIdx.x;
  const int wg    = blockIdx.x;
  const bool isL0 = wg < NWG0;
  const int lw    = isL0 ? wg : wg - NWG0;
  const int H     = isL0 ? H0 : H1;
  const int jbase = lw * 4;            // 4 h-cols per WG
  const int lane  = tid & 63;
  const int mt    = tid >> 6;          // wave id = m-tile (16 batches)
  const int n     = lane & 15;         // MFMA n-index / A row-in-tile
  const int quad  = lane >> 4;
  // n -> gate (n>>2 in {i,f,g,o}), h-col jbase + (n&3)
  const int gcol  = (n >> 2) * H + jbase + (n & 3);
  const int brow  = mt * 16 + n;       // batch row this lane loads for A

  // ---- prologue: gather weight B-fragments; hi-plane -> VGPRs, lo -> LDS ----
  v4u wfa[NKT];
  {
    const float* Wi = isL0 ? Wih0 : Wih1;
    const float* Wh = isL0 ? Whh0 : Whh1;
    const int Ki  = isL0 ? DIN : H0;
    const int ldw = 4 * H;
    #pragma unroll
    for (int kt = 0; kt < NKT; ++kt){
      const int ks = kt * 32 + quad * 8;
      float w[8];
      #pragma unroll
      for (int j = 0; j < 8; ++j){
        const int k = ks + j;
        w[j] = (k < Ki) ? Wi[(size_t)k * ldw + gcol]
                        : Wh[(size_t)(k - Ki) * ldw + gcol];
      }
      v4u ua, ub;
      #pragma unroll
      for (int d = 0; d < 4; ++d){
        const unsigned p = pk2(w[2*d], w[2*d+1]);
        ua[d] = p;
        ub[d] = pk2(w[2*d] - lo16(p), w[2*d+1] - hi16(p));
      }
      wfa[kt] = ua;
      if (mt == 0) wfbs[kt * 64 + lane] = ub;   // fragments identical across waves
    }
  }
  const float bsum = isL0 ? (bih0[gcol] + bhh0[gcol]) : (bih1[gcol] + bhh1[gcol]);

  float c0 = 0.f, c1 = 0.f, c2 = 0.f, c3 = 0.f;   // cell state (lanes n<4)
  __syncthreads();

  for (int t = 0; t < TT; ++t){
    // ---- wait for dependencies (tid0 spins, rest at barrier) ----
    if (tid == 0){
      if (isL0){
        if (t >= 1) spinw(cnt0 + (t - 1), NWG0);  // h1(t-1) ready
        if (t >= 2) spinw(cnt1 + (t - 2), NWG1);  // h1 slot free of L1 readers
      } else {
        spinw(cnt0 + t, NWG0);                    // h1(t) ready
        if (t >= 1) spinw(cnt1 + (t - 1), NWG1);  // h2(t-1) ready + slot free
      }
    }
    __syncthreads();

    v4f acc1 = { bsum, bsum, bsum, bsum };
    v4f acc2 = { 0.f, 0.f, 0.f, 0.f };

    if (isL0){
      // k 0..255 : x_t
      if (use_xp){
        const unsigned* xr = xp + ((size_t)brow * TT + t) * DIN + quad * 8;
        #pragma unroll
        for (int kt = 0; kt < 8; ++kt){
          v4u p0 = *(const v4u*)(xr + kt * 32);
          v4u p1 = *(const v4u*)(xr + kt * 32 + 4);
          v8h A, Ab; frag_from_pairs(p0, p1, A, Ab);
          v8h Wa = as_h8(wfa[kt]), Wb = as_h8(wfbs[kt * 64 + lane]);
          acc1 = mfma16(A,  Wa, acc1);
          acc2 = mfma16(A,  Wb, acc2);
          acc2 = mfma16(Ab, Wa, acc2);
        }
      } else {
        const float* xr = x + ((size_t)brow * TT + t) * DIN + quad * 8;
        #pragma unroll
        for (int kt = 0; kt < 8; ++kt){
          v4f f0 = *(const v4f*)(xr + kt * 32);
          v4f f1 = *(const v4f*)(xr + kt * 32 + 4);
          v8h A, Ab; frag_from_floats(f0, f1, A, Ab);
          v8h Wa = as_h8(wfa[kt]), Wb = as_h8(wfbs[kt * 64 + lane]);
          acc1 = mfma16(A,  Wa, acc1);
          acc2 = mfma16(A,  Wb, acc2);
          acc2 = mfma16(Ab, Wa, acc2);
        }
      }
      // k 256..767 : h1(t-1), slot (t+1)&1
      const unsigned* hr = h1p + (size_t)((t + 1) & 1) * (BB * H0)
                               + (size_t)brow * H0 + quad * 8;
      #pragma unroll
      for (int kt = 0; kt < 16; ++kt){
        v4u p0 = *(const v4u*)(hr + kt * 32);
        v4u p1 = *(const v4u*)(hr + kt * 32 + 4);
        v8h A, Ab; frag_from_pairs(p0, p1, A, Ab);
        v8h Wa = as_h8(wfa[kt + 8]), Wb = as_h8(wfbs[(kt + 8) * 64 + lane]);
        acc1 = mfma16(A,  Wa, acc1);
        acc2 = mfma16(A,  Wb, acc2);
        acc2 = mfma16(Ab, Wa, acc2);
      }
    } else {
      // k 0..511 : h1(t), slot t&1
      const unsigned* hr = h1p + (size_t)(t & 1) * (BB * H0)
                               + (size_t)brow * H0 + quad * 8;
      #pragma unroll
      for (int kt = 0; kt < 16; ++kt){
        v4u p0 = *(const v4u*)(hr + kt * 32);
        v4u p1 = *(const v4u*)(hr + kt * 32 + 4);
        v8h A, Ab; frag_from_pairs(p0, p1, A, Ab);
        v8h Wa = as_h8(wfa[kt]), Wb = as_h8(wfbs[kt * 64 + lane]);
        acc1 = mfma16(A,  Wa, acc1);
        acc2 = mfma16(A,  Wb, acc2);
        acc2 = mfma16(Ab, Wa, acc2);
      }
      // k 512..767 : h2(t-1), slot (t+1)&1
      const unsigned* h2r = h2p + (size_t)((t + 1) & 1) * (BB * H1)
                                + (size_t)brow * H1 + quad * 8;
      #pragma unroll
      for (int kt = 0; kt < 8; ++kt){
        v4u p0 = *(const v4u*)(h2r + kt * 32);
        v4u p1 = *(const v4u*)(h2r + kt * 32 + 4);
        v8h A, Ab; frag_from_pairs(p0, p1, A, Ab);
        v8h Wa = as_h8(wfa[kt + 16]), Wb = as_h8(wfbs[(kt + 16) * 64 + lane]);
        acc1 = mfma16(A,  Wa, acc1);
        acc2 = mfma16(A,  Wb, acc2);
        acc2 = mfma16(Ab, Wa, acc2);
      }
    }

    // ---- elementwise LSTM: gather (i,f,g,o) per (b, h-col) via 2 shfl_xor ----
    v4f gv = acc1 + acc2;
    float pv0 = __shfl_xor(gv[0], 4), pv1 = __shfl_xor(gv[1], 4),
          pv2 = __shfl_xor(gv[2], 4), pv3 = __shfl_xor(gv[3], 4);
    float qv0 = __shfl_xor(gv[0], 8), qv1 = __shfl_xor(gv[1], 8),
          qv2 = __shfl_xor(gv[2], 8), qv3 = __shfl_xor(gv[3], 8);
    float sv0 = __shfl_xor(pv0, 8), sv1 = __shfl_xor(pv1, 8),
          sv2 = __shfl_xor(pv2, 8), sv3 = __shfl_xor(pv3, 8);

    if (n < 4){
      // lane n<4: i = gv, f = pv, g = qv, o = sv ; rows b = mt*16 + quad*4 + r
      float iv[4] = { gv[0], gv[1], gv[2], gv[3] };
      float fv[4] = { pv0, pv1, pv2, pv3 };
      float gg[4] = { qv0, qv1, qv2, qv3 };
      float ov[4] = { sv0, sv1, sv2, sv3 };
      float cc[4] = { c0, c1, c2, c3 };
      const int col = jbase + n;
      #pragma unroll
      for (int r = 0; r < 4; ++r){
        float cn = sigf(fv[r]) * cc[r] + sigf(iv[r]) * tanhf_(gg[r]);
        float hn = sigf(ov[r]) * tanhf_(cn);
        cc[r] = cn;
        const int b = mt * 16 + quad * 4 + r;
        unsigned pa = pk2(hn, 0.f);
        unsigned pd = pk2(hn, hn - lo16(pa));
        if (isL0){
          __hip_atomic_store(h1p + (size_t)(t & 1) * (BB * H0) + (size_t)b * H0 + col,
                             pd, __ATOMIC_RELAXED, __HIP_MEMORY_SCOPE_AGENT);
        } else {
          __hip_atomic_store(h2p + (size_t)(t & 1) * (BB * H1) + (size_t)b * H1 + col,
                             pd, __ATOMIC_RELAXED, __HIP_MEMORY_SCOPE_AGENT);
          out[((size_t)b * TT + t) * H1 + col] = hn;
        }
      }
      c0 = cc[0]; c1 = cc[1]; c2 = cc[2]; c3 = cc[3];
    }

    // ---- publish: barrier drains vmcnt, then one release add per WG ----
    __syncthreads();
    if (tid == 0){
      __hip_atomic_fetch_add(isL0 ? (cnt0 + t) : (cnt1 + t), 1u,
                             __ATOMIC_RELEASE, __HIP_MEMORY_SCOPE_AGENT);
    }
  }
}

__global__ void init_ws(unsigned* ws, int nz){
  int i = blockIdx.x * blockDim.x + threadIdx.x;
  if (i < nz) ws[i] = 0u;
}

__global__ void conv_x(const float4* __restrict__ x4, v4u* __restrict__ xp4, int n4){
  int i = blockIdx.x * blockDim.x + threadIdx.x;
  if (i >= n4) return;
  float4 f = x4[i];
  float v[4] = { f.x, f.y, f.z, f.w };
  v4u o;
  #pragma unroll
  for (int d = 0; d < 4; ++d){
    unsigned p = pk2(v[d], 0.f);
    o[d] = pk2(v[d], v[d] - lo16(p));
  }
  xp4[i] = o;
}

extern "C" void kernel_launch(void* const* d_in, const int* in_sizes, int n_in,
                              void* d_out, int out_size, void* d_ws, size_t ws_size,
                              hipStream_t stream) {
  const float* x    = (const float*)d_in[0];
  const float* Wih0 = (const float*)d_in[1];
  const float* bih0 = (const float*)d_in[2];
  const float* Whh0 = (const float*)d_in[3];
  const float* bhh0 = (const float*)d_in[4];
  const float* Wih1 = (const float*)d_in[5];
  const float* bih1 = (const float*)d_in[6];
  const float* Whh1 = (const float*)d_in[7];
  const float* bhh1 = (const float*)d_in[8];
  float* outp = (float*)d_out;

  unsigned* ws   = (unsigned*)d_ws;
  unsigned* h1p  = ws;                       // 2*64*512  = 65536 dwords
  unsigned* h2p  = h1p + 2 * BB * H0;        // 2*64*256  = 32768
  unsigned* cnt0 = h2p + 2 * BB * H1;        // 1024
  unsigned* cnt1 = cnt0 + TT;                // 1024
  unsigned* xp   = cnt1 + TT;                // optional: B*T*DIN pair dwords
  const int nz = 2 * BB * H0 + 2 * BB * H1 + 2 * TT;   // 100352 dwords to zero

  const size_t need_xp = ((size_t)nz + (size_t)BB * TT * DIN) * 4;
  int use_xp = (ws_size >= need_xp) ? 1 : 0;

  init_ws<<<dim3((nz + 255) / 256), dim3(256), 0, stream>>>(ws, nz);
  if (use_xp){
    const int n4 = BB * TT * DIN / 4;
    conv_x<<<dim3((n4 + 255) / 256), dim3(256), 0, stream>>>((const float4*)x, (v4u*)xp, n4);
  }

  lstm_mfma<<<dim3(NWG), dim3(NTHR), 0, stream>>>(
      x, xp, use_xp,
      Wih0, bih0, Whh0, bhh0,
      Wih1, bih1, Whh1, bhh1,
      h1p, h2p, cnt0, cnt1, outp);
}

// Round 5
// 15767.468 us; speedup vs baseline: 4.7026x; 1.1694x over previous
//
#include <hip/hip_runtime.h>

// ---------------------------------------------------------------------------
// V3: persistent MFMA LSTM, fence-free step loop.
//  - f16 two-plane split (hi/lo), 3 x mfma_f32_16x16x32_f16 per k-tile
//  - hi-plane weights in VGPRs/AGPRs, lo-plane weights in LDS (shared copy)
//  - cross-WG protocol: producers store h write-through (atomic relaxed agent,
//    sc0 sc1), barrier drains vmcnt, then RELAXED fetch_add (no buffer_wbl2).
//    Consumers poll relaxed and read h via 8B relaxed agent atomic loads
//    (sc0 sc1) -- no buffer_inv, L2-cached x/weights stay warm.
//  - L0: WGs 0..127 compute x-part before spinning; L1: WGs 128..191 compute
//    h2-part before spinning on L0's counter. Pipelined 1 step.
// ---------------------------------------------------------------------------

constexpr int BB   = 64;
constexpr int TT   = 1024;
constexpr int DIN  = 256;
constexpr int H0   = 512;
constexpr int H1   = 256;
constexpr int NWG0 = 128;
constexpr int NWG1 = 64;
constexpr int NWG  = NWG0 + NWG1;
constexpr int NTHR = 256;
constexpr int NKT  = 24;       // K = 768 = 24 tiles of 32

typedef _Float16 v8h __attribute__((ext_vector_type(8)));
typedef __fp16   v2p __attribute__((ext_vector_type(2)));   // cvt_pkrtz result type
typedef float    v4f __attribute__((ext_vector_type(4)));
typedef unsigned int v4u __attribute__((ext_vector_type(4)));

union U1 { unsigned u; v2p h; };
union U4 { v4u u; v8h h; };

__device__ __forceinline__ unsigned pk2(float a, float b){
  U1 c; c.h = __builtin_amdgcn_cvt_pkrtz(a, b); return c.u;
}
__device__ __forceinline__ float lo16(unsigned u){ U1 c; c.u = u; return (float)c.h[0]; }
__device__ __forceinline__ float hi16(unsigned u){ U1 c; c.u = u; return (float)c.h[1]; }
__device__ __forceinline__ v8h as_h8(v4u u){ U4 c; c.u = u; return c.h; }

__device__ __forceinline__ v4f mfma16(v8h a, v8h b, v4f c){
  return __builtin_amdgcn_mfma_f32_16x16x32_f16(a, b, c, 0, 0, 0);
}

__device__ __forceinline__ float sigf(float v){ return 1.0f / (1.0f + __expf(-v)); }
__device__ __forceinline__ float tanhf_(float v){
  float e = __expf(2.0f * v);
  return 1.0f - 2.0f / (e + 1.0f);     // inf-safe
}

// pure relaxed poll: no acquire, no cache invalidate (data is read via sc1
// atomic loads, so no stale-cache hazard exists for it)
__device__ __forceinline__ void spinw(const unsigned* p, unsigned tgt){
  while (__hip_atomic_load(p, __ATOMIC_RELAXED, __HIP_MEMORY_SCOPE_AGENT) < tgt)
    __builtin_amdgcn_s_sleep(1);
}

// 32B of pair-dwords via 4 x 8B agent-scope relaxed atomic loads (sc0 sc1:
// miss L1/L2, read from the coherence point -> always fresh, no inv needed)
__device__ __forceinline__ void load_pairs_sc(const unsigned* p, v4u& p0, v4u& p1){
  const unsigned long long* q = (const unsigned long long*)p;
  unsigned long long a = __hip_atomic_load(q + 0, __ATOMIC_RELAXED, __HIP_MEMORY_SCOPE_AGENT);
  unsigned long long b = __hip_atomic_load(q + 1, __ATOMIC_RELAXED, __HIP_MEMORY_SCOPE_AGENT);
  unsigned long long c = __hip_atomic_load(q + 2, __ATOMIC_RELAXED, __HIP_MEMORY_SCOPE_AGENT);
  unsigned long long d = __hip_atomic_load(q + 3, __ATOMIC_RELAXED, __HIP_MEMORY_SCOPE_AGENT);
  p0[0] = (unsigned)a; p0[1] = (unsigned)(a >> 32);
  p0[2] = (unsigned)b; p0[3] = (unsigned)(b >> 32);
  p1[0] = (unsigned)c; p1[1] = (unsigned)(c >> 32);
  p1[2] = (unsigned)d; p1[3] = (unsigned)(d >> 32);
}

// pack two pair-dword quads into hi-plane / lo-plane A fragments
__device__ __forceinline__ void frag_from_pairs(v4u p0, v4u p1, v8h& A, v8h& B){
  v4u ua, ub;
  ua[0] = __builtin_amdgcn_perm(p0[1], p0[0], 0x05040100u);
  ua[1] = __builtin_amdgcn_perm(p0[3], p0[2], 0x05040100u);
  ua[2] = __builtin_amdgcn_perm(p1[1], p1[0], 0x05040100u);
  ua[3] = __builtin_amdgcn_perm(p1[3], p1[2], 0x05040100u);
  ub[0] = __builtin_amdgcn_perm(p0[1], p0[0], 0x07060302u);
  ub[1] = __builtin_amdgcn_perm(p0[3], p0[2], 0x07060302u);
  ub[2] = __builtin_amdgcn_perm(p1[1], p1[0], 0x07060302u);
  ub[3] = __builtin_amdgcn_perm(p1[3], p1[2], 0x07060302u);
  A = as_h8(ua); B = as_h8(ub);
}

__device__ __forceinline__ void frag_from_floats(v4f f0, v4f f1, v8h& A, v8h& B){
  float v[8] = { f0[0], f0[1], f0[2], f0[3], f1[0], f1[1], f1[2], f1[3] };
  v4u ua, ub;
  #pragma unroll
  for (int d = 0; d < 4; ++d){
    unsigned p = pk2(v[2*d], v[2*d+1]);
    ua[d] = p;
    ub[d] = pk2(v[2*d] - lo16(p), v[2*d+1] - hi16(p));
  }
  A = as_h8(ua); B = as_h8(ub);
}

__global__ void __launch_bounds__(NTHR, 1)
lstm_mfma(const float* __restrict__ x, const unsigned* __restrict__ xp, int use_xp,
          const float* __restrict__ Wih0, const float* __restrict__ bih0,
          const float* __restrict__ Whh0, const float* __restrict__ bhh0,
          const float* __restrict__ Wih1, const float* __restrict__ bih1,
          const float* __restrict__ Whh1, const float* __restrict__ bhh1,
          unsigned* h1p, unsigned* h2p,
          unsigned* cnt0, unsigned* cnt1,
          float* out)
{
  __shared__ v4u wfbs[NKT * 64];       // 24 KB: lo-plane weight B-fragments

  const int tid   = threadIdx.x;
  const int wg    = blockIdx.x;
  const bool isL0 = wg < NWG0;
  const int lw    = isL0 ? wg : wg - NWG0;
  const int H     = isL0 ? H0 : H1;
  const int jbase = lw * 4;            // 4 h-cols per WG
  const int lane  = tid & 63;
  const int mt    = tid >> 6;          // wave id = m-tile (16 batches)
  const int n     = lane & 15;         // MFMA n-index / A row-in-tile
  const int quad  = lane >> 4;
  // n -> gate (n>>2 in {i,f,g,o}), h-col jbase + (n&3)
  const int gcol  = (n >> 2) * H + jbase + (n & 3);
  const int brow  = mt * 16 + n;       // batch row this lane loads for A

  // ---- prologue: gather weight B-fragments; hi-plane -> VGPRs, lo -> LDS ----
  v4u wfa[NKT];
  {
    const float* Wi = isL0 ? Wih0 : Wih1;
    const float* Wh = isL0 ? Whh0 : Whh1;
    const int Ki  = isL0 ? DIN : H0;
    const int ldw = 4 * H;
    #pragma unroll
    for (int kt = 0; kt < NKT; ++kt){
      const int ks = kt * 32 + quad * 8;
      float w[8];
      #pragma unroll
      for (int j = 0; j < 8; ++j){
        const int k = ks + j;
        w[j] = (k < Ki) ? Wi[(size_t)k * ldw + gcol]
                        : Wh[(size_t)(k - Ki) * ldw + gcol];
      }
      v4u ua, ub;
      #pragma unroll
      for (int d = 0; d < 4; ++d){
        const unsigned p = pk2(w[2*d], w[2*d+1]);
        ua[d] = p;
        ub[d] = pk2(w[2*d] - lo16(p), w[2*d+1] - hi16(p));
      }
      wfa[kt] = ua;
      if (mt == 0) wfbs[kt * 64 + lane] = ub;   // fragments identical across waves
    }
  }
  const float bsum = isL0 ? (bih0[gcol] + bhh0[gcol]) : (bih1[gcol] + bhh1[gcol]);

  float c0 = 0.f, c1 = 0.f, c2 = 0.f, c3 = 0.f;   // cell state (lanes n<4)
  __syncthreads();

  for (int t = 0; t < TT; ++t){
    v4f acc1 = { bsum, bsum, bsum, bsum };
    v4f acc2 = { 0.f, 0.f, 0.f, 0.f };

    if (isL0){
      // ---- x-part first: no cross-WG dependency, hides the spin ----
      if (use_xp){
        const unsigned* xr = xp + ((size_t)brow * TT + t) * DIN + quad * 8;
        #pragma unroll
        for (int kt = 0; kt < 8; ++kt){
          v4u p0 = *(const v4u*)(xr + kt * 32);
          v4u p1 = *(const v4u*)(xr + kt * 32 + 4);
          v8h A, Ab; frag_from_pairs(p0, p1, A, Ab);
          v8h Wa = as_h8(wfa[kt]), Wb = as_h8(wfbs[kt * 64 + lane]);
          acc1 = mfma16(A,  Wa, acc1);
          acc2 = mfma16(A,  Wb, acc2);
          acc2 = mfma16(Ab, Wa, acc2);
        }
      } else {
        const float* xr = x + ((size_t)brow * TT + t) * DIN + quad * 8;
        #pragma unroll
        for (int kt = 0; kt < 8; ++kt){
          v4f f0 = *(const v4f*)(xr + kt * 32);
          v4f f1 = *(const v4f*)(xr + kt * 32 + 4);
          v8h A, Ab; frag_from_floats(f0, f1, A, Ab);
          v8h Wa = as_h8(wfa[kt]), Wb = as_h8(wfbs[kt * 64 + lane]);
          acc1 = mfma16(A,  Wa, acc1);
          acc2 = mfma16(A,  Wb, acc2);
          acc2 = mfma16(Ab, Wa, acc2);
        }
      }
      // ---- wait for h1(t-1) ----
      if (tid == 0 && t >= 1) spinw(cnt0 + (t - 1), NWG0);
      __syncthreads();
      // ---- h1(t-1) part, slot (t+1)&1, fresh sc1 loads ----
      const unsigned* hr = h1p + (size_t)((t + 1) & 1) * (BB * H0)
                               + (size_t)brow * H0 + quad * 8;
      #pragma unroll
      for (int kt = 0; kt < 16; ++kt){
        v4u p0, p1; load_pairs_sc(hr + kt * 32, p0, p1);
        v8h A, Ab; frag_from_pairs(p0, p1, A, Ab);
        v8h Wa = as_h8(wfa[kt + 8]), Wb = as_h8(wfbs[(kt + 8) * 64 + lane]);
        acc1 = mfma16(A,  Wa, acc1);
        acc2 = mfma16(A,  Wb, acc2);
        acc2 = mfma16(Ab, Wa, acc2);
      }
      // ---- slot-free guard before storing h1(t) over h1(t-2) ----
      if (tid == 0 && t >= 2) spinw(cnt1 + (t - 2), NWG1);
      __syncthreads();
    } else {
      // ---- h2(t-1) part first: own-layer dep (cnt1), usually ready ----
      if (tid == 0 && t >= 1) spinw(cnt1 + (t - 1), NWG1);
      __syncthreads();
      const unsigned* h2r = h2p + (size_t)((t + 1) & 1) * (BB * H1)
                                + (size_t)brow * H1 + quad * 8;
      #pragma unroll
      for (int kt = 0; kt < 8; ++kt){
        v4u p0, p1; load_pairs_sc(h2r + kt * 32, p0, p1);
        v8h A, Ab; frag_from_pairs(p0, p1, A, Ab);
        v8h Wa = as_h8(wfa[kt + 16]), Wb = as_h8(wfbs[(kt + 16) * 64 + lane]);
        acc1 = mfma16(A,  Wa, acc1);
        acc2 = mfma16(A,  Wb, acc2);
        acc2 = mfma16(Ab, Wa, acc2);
      }
      // ---- wait for h1(t) ----
      if (tid == 0) spinw(cnt0 + t, NWG0);
      __syncthreads();
      const unsigned* hr = h1p + (size_t)(t & 1) * (BB * H0)
                               + (size_t)brow * H0 + quad * 8;
      #pragma unroll
      for (int kt = 0; kt < 16; ++kt){
        v4u p0, p1; load_pairs_sc(hr + kt * 32, p0, p1);
        v8h A, Ab; frag_from_pairs(p0, p1, A, Ab);
        v8h Wa = as_h8(wfa[kt]), Wb = as_h8(wfbs[kt * 64 + lane]);
        acc1 = mfma16(A,  Wa, acc1);
        acc2 = mfma16(A,  Wb, acc2);
        acc2 = mfma16(Ab, Wa, acc2);
      }
    }

    // ---- elementwise LSTM: gather (i,f,g,o) per (b, h-col) via 2 shfl_xor ----
    v4f gv = acc1 + acc2;
    float pv0 = __shfl_xor(gv[0], 4), pv1 = __shfl_xor(gv[1], 4),
          pv2 = __shfl_xor(gv[2], 4), pv3 = __shfl_xor(gv[3], 4);
    float qv0 = __shfl_xor(gv[0], 8), qv1 = __shfl_xor(gv[1], 8),
          qv2 = __shfl_xor(gv[2], 8), qv3 = __shfl_xor(gv[3], 8);
    float sv0 = __shfl_xor(pv0, 8), sv1 = __shfl_xor(pv1, 8),
          sv2 = __shfl_xor(pv2, 8), sv3 = __shfl_xor(pv3, 8);

    if (n < 4){
      // lane n<4: i = gv, f = pv, g = qv, o = sv ; rows b = mt*16 + quad*4 + r
      float iv[4] = { gv[0], gv[1], gv[2], gv[3] };
      float fv[4] = { pv0, pv1, pv2, pv3 };
      float gg[4] = { qv0, qv1, qv2, qv3 };
      float ov[4] = { sv0, sv1, sv2, sv3 };
      float cc[4] = { c0, c1, c2, c3 };
      const int col = jbase + n;
      #pragma unroll
      for (int r = 0; r < 4; ++r){
        float cn = sigf(fv[r]) * cc[r] + sigf(iv[r]) * tanhf_(gg[r]);
        float hn = sigf(ov[r]) * tanhf_(cn);
        cc[r] = cn;
        const int b = mt * 16 + quad * 4 + r;
        unsigned pa = pk2(hn, 0.f);
        unsigned pd = pk2(hn, hn - lo16(pa));
        if (isL0){
          __hip_atomic_store(h1p + (size_t)(t & 1) * (BB * H0) + (size_t)b * H0 + col,
                             pd, __ATOMIC_RELAXED, __HIP_MEMORY_SCOPE_AGENT);
        } else {
          __hip_atomic_store(h2p + (size_t)(t & 1) * (BB * H1) + (size_t)b * H1 + col,
                             pd, __ATOMIC_RELAXED, __HIP_MEMORY_SCOPE_AGENT);
          out[((size_t)b * TT + t) * H1 + col] = hn;
        }
      }
      c0 = cc[0]; c1 = cc[1]; c2 = cc[2]; c3 = cc[3];
    }

    // ---- publish: barrier drains vmcnt (stores are write-through sc1, so
    // they are at the coherence point once retired) -> RELAXED add suffices ----
    __syncthreads();
    if (tid == 0){
      __hip_atomic_fetch_add(isL0 ? (cnt0 + t) : (cnt1 + t), 1u,
                             __ATOMIC_RELAXED, __HIP_MEMORY_SCOPE_AGENT);
    }
  }
}

__global__ void init_ws(unsigned* ws, int nz){
  int i = blockIdx.x * blockDim.x + threadIdx.x;
  if (i < nz) ws[i] = 0u;
}

__global__ void conv_x(const float4* __restrict__ x4, v4u* __restrict__ xp4, int n4){
  int i = blockIdx.x * blockDim.x + threadIdx.x;
  if (i >= n4) return;
  float4 f = x4[i];
  float v[4] = { f.x, f.y, f.z, f.w };
  v4u o;
  #pragma unroll
  for (int d = 0; d < 4; ++d){
    unsigned p = pk2(v[d], 0.f);
    o[d] = pk2(v[d], v[d] - lo16(p));
  }
  xp4[i] = o;
}

extern "C" void kernel_launch(void* const* d_in, const int* in_sizes, int n_in,
                              void* d_out, int out_size, void* d_ws, size_t ws_size,
                              hipStream_t stream) {
  const float* x    = (const float*)d_in[0];
  const float* Wih0 = (const float*)d_in[1];
  const float* bih0 = (const float*)d_in[2];
  const float* Whh0 = (const float*)d_in[3];
  const float* bhh0 = (const float*)d_in[4];
  const float* Wih1 = (const float*)d_in[5];
  const float* bih1 = (const float*)d_in[6];
  const float* Whh1 = (const float*)d_in[7];
  const float* bhh1 = (const float*)d_in[8];
  float* outp = (float*)d_out;

  unsigned* ws   = (unsigned*)d_ws;
  unsigned* h1p  = ws;                       // 2*64*512  = 65536 dwords
  unsigned* h2p  = h1p + 2 * BB * H0;        // 2*64*256  = 32768
  unsigned* cnt0 = h2p + 2 * BB * H1;        // 1024
  unsigned* cnt1 = cnt0 + TT;                // 1024
  unsigned* xp   = cnt1 + TT;                // optional: B*T*DIN pair dwords
  const int nz = 2 * BB * H0 + 2 * BB * H1 + 2 * TT;   // 100352 dwords to zero

  const size_t need_xp = ((size_t)nz + (size_t)BB * TT * DIN) * 4;
  int use_xp = (ws_size >= need_xp) ? 1 : 0;

  init_ws<<<dim3((nz + 255) / 256), dim3(256), 0, stream>>>(ws, nz);
  if (use_xp){
    const int n4 = BB * TT * DIN / 4;
    conv_x<<<dim3((n4 + 255) / 256), dim3(256), 0, stream>>>((const float4*)x, (v4u*)xp, n4);
  }

  lstm_mfma<<<dim3(NWG), dim3(NTHR), 0, stream>>>(
      x, xp, use_xp,
      Wih0, bih0, Whh0, bhh0,
      Wih1, bih1, Whh1, bhh1,
      h1p, h2p, cnt0, cnt1, outp);
}